// Round 18
// baseline (72.586 us; speedup 1.0000x reference)
//
#include <hip/hip_runtime.h>
#include <hip/hip_bf16.h>
#include <math.h>

#define TOK 16384
#define HDIM 2048
#define NE 64
#define NB 4
#define KTOP 8
#define NC 32            // 64-k chunks in wpk layout
#define NC2 64           // 32-k pipeline chunks
#define BT 32            // tokens per block

typedef __attribute__((ext_vector_type(8))) __bf16 bf16x8;
typedef __attribute__((ext_vector_type(4))) float f32x4;
typedef unsigned int uint;

__device__ __forceinline__ uint asu(float f) { union { float f; uint u; } c; c.f = f; return c.u; }
__device__ __forceinline__ float asf(uint u) { union { uint u; float f; } c; c.u = u; return c.f; }

// Exact 3-way bf16 split: h+m+l == x bitwise (8 mantissa bits per plane).
__device__ __forceinline__ void split3(float v, uint& h, uint& m, uint& l) {
  uint u = asu(v);
  h = u & 0xffff0000u;
  float d = v - asf(h);
  m = asu(d) & 0xffff0000u;
  float d2 = d - asf(m);
  l = asu(d2);
}

// 8 floats (one fragment k-slot) -> 3 bf16x8 planes, in-register.
__device__ __forceinline__ void split8(float4 a, float4 b,
                                       bf16x8& h8, bf16x8& m8, bf16x8& l8) {
  union { uint4 u; bf16x8 v; } H, M, L;
  uint h0, m0, l0, h1, m1, l1;
  split3(a.x, h0, m0, l0); split3(a.y, h1, m1, l1);
  H.u.x = (h0 >> 16) | (h1 & 0xffff0000u);
  M.u.x = (m0 >> 16) | (m1 & 0xffff0000u);
  L.u.x = (l0 >> 16) | (l1 & 0xffff0000u);
  split3(a.z, h0, m0, l0); split3(a.w, h1, m1, l1);
  H.u.y = (h0 >> 16) | (h1 & 0xffff0000u);
  M.u.y = (m0 >> 16) | (m1 & 0xffff0000u);
  L.u.y = (l0 >> 16) | (l1 & 0xffff0000u);
  split3(b.x, h0, m0, l0); split3(b.y, h1, m1, l1);
  H.u.z = (h0 >> 16) | (h1 & 0xffff0000u);
  M.u.z = (m0 >> 16) | (m1 & 0xffff0000u);
  L.u.z = (l0 >> 16) | (l1 & 0xffff0000u);
  split3(b.z, h0, m0, l0); split3(b.w, h1, m1, l1);
  H.u.w = (h0 >> 16) | (h1 & 0xffff0000u);
  M.u.w = (m0 >> 16) | (m1 & 0xffff0000u);
  L.u.w = (l0 >> 16) | (l1 & 0xffff0000u);
  h8 = H.v; m8 = M.v; l8 = L.v;
}

__device__ __forceinline__ void gl_lds16(const void* g, void* l) {
  __builtin_amdgcn_global_load_lds(
      (const __attribute__((address_space(1))) void*)g,
      (__attribute__((address_space(3))) void*)l, 16, 0, 0);
}

// ---------------------------------------------------------------------------
// wsplit (r16-verbatim): pack W into B-fragment order, 3 exact bf16 planes;
// zero ce/ssum. byte = c64*24576 + ks*12288 + half*6144 + f2*3072
//                     + plane*1024 + lane*16
// ---------------------------------------------------------------------------
__global__ __launch_bounds__(256) void wsplit(const float* __restrict__ w,
                                              char* __restrict__ wpk,
                                              float* __restrict__ stats) {
  if (blockIdx.x == 0 && threadIdx.x < 128) {   // zero ce+ssum (512 floats)
    *(float4*)(stats + threadIdx.x * 4) = make_float4(0.f, 0.f, 0.f, 0.f);
  }
  int t = blockIdx.x * 256 + threadIdx.x;    // 16384 threads
  int lane = t & 63;
  int f2 = (t >> 6) & 1, half = (t >> 7) & 1, ks = (t >> 8) & 1, c = t >> 9;
  int e = half * 32 + f2 * 16 + (lane & 15);
  int k = c * 64 + ks * 32 + ((lane >> 4) << 3);
  const float* p = w + (size_t)e * HDIM + k;
  bf16x8 h8, m8, l8;
  split8(*(const float4*)p, *(const float4*)(p + 4), h8, m8, l8);
  union { bf16x8 v; uint4 u; } H, M, L;
  H.v = h8; M.v = m8; L.v = l8;
  size_t base = (size_t)c * 24576 + (size_t)ks * 12288 + (size_t)half * 6144
              + (size_t)f2 * 3072 + (size_t)lane * 16;
  *(uint4*)(wpk + base) = H.u;
  *(uint4*)(wpk + base + 1024) = M.u;
  *(uint4*)(wpk + base + 2048) = L.u;
}

// ---------------------------------------------------------------------------
// Fused gate = r16 substrate (all-gl_lds staging, 2 blocks/CU, 16 tok x 32
// exp waves, bitwise-identical MFMA order) + T4 counted-vmcnt tri-buffer:
//   - chunk = 32 k (64 chunks); per chunk per thread exactly 4 gl_lds ops
//     (3x W 12 KB + 1x X 4 KB), tri-buffered (3x16 KB = 48 KB LDS).
//   - per chunk: issue stage(c+2) -> compute chunk c -> s_waitcnt vmcnt(4)
//     (drains stage(c+1), the OLDEST 4; stage(c+2) stays in flight) ->
//     barrier. The drain always targets loads issued a FULL chunk earlier,
//     so gl_lds delivery pipelines across barriers (r16 drained vmcnt(0)
//     per chunk = T4 violation; r17 falsified the raw staged-bytes model).
// NO register global loads (r5/r8/r10 poison). NO threadfence (r15 poison).
// ---------------------------------------------------------------------------
__global__ __launch_bounds__(256, 2) void gate_fused(const float* __restrict__ x,
                                                     const char* __restrict__ wpk,
                                                     float* __restrict__ out,
                                                     float* __restrict__ ce,
                                                     float* __restrict__ ssum) {
  __shared__ __align__(16) char lds[49152];   // W tri 3x12K @0 | X tri 3x4K @36864
  __shared__ float hist[NE];

  const int tid = threadIdx.x;
  const int bid = blockIdx.x;
  const int t0 = bid * BT;
  const int b = bid >> 7;                     // 128 blocks per batch row
  const int lane = tid & 63;
  const int wid = tid >> 6;                   // 0..3
  const int half = wid & 1;                   // expert half
  const int tg = (wid >> 1);                  // token group: 0 or 1

  if (tid < NE) hist[tid] = 0.f;

  // X staging (m173): slot s = tid = [tg(1b)][q(1b)][ln(6b)]; content
  // x[t0 + stg*16 + (ln&15)][c*32 + (ln>>4)*8 + sq*4 .. +3].
  // Per-lane source; wave-uniform dest (+ lane*16 by HW).
  const int stg = tid >> 7, sq = (tid >> 6) & 1;
  const char* xsg = (const char*)(x + (size_t)(t0 + stg * 16 + (lane & 15)) * HDIM
                                  + ((lane >> 4) << 3) + sq * 4);
  const int xdo_ = wid * 1024;                // wave-uniform dest offset
  const char* wsrc = wpk + (size_t)lane * 16;

  f32x4 acc[2] = {{0.f, 0.f, 0.f, 0.f}, {0.f, 0.f, 0.f, 0.f}};

  // stage chunk cc (32-k): W = wpk[(cc>>1)*24576 + (cc&1)*12288, 12 KB),
  // X advances 32 floats = 128 B per chunk. Buffer slot = cc % 3.
#define STAGE(cc)                                                             \
  {                                                                           \
    const char* wp_ = wsrc + (size_t)((cc) >> 1) * 24576 + ((cc) & 1) * 12288; \
    char* wd_ = lds + ((cc) % 3) * 12288;                                     \
    _Pragma("unroll")                                                         \
    for (int i = 0; i < 3; ++i)                                               \
      gl_lds16(wp_ + (i * 4 + wid) * 1024, wd_ + (i * 4 + wid) * 1024);       \
    gl_lds16(xsg + (size_t)(cc) * 128, lds + 36864 + ((cc) % 3) * 4096 + xdo_); \
  }

  // ---- prologue: stage(0), stage(1); drain stage(0) (oldest 4), barrier
  STAGE(0);
  STAGE(1);
  asm volatile("s_waitcnt vmcnt(4)" ::: "memory");
  __builtin_amdgcn_s_barrier();
  asm volatile("" ::: "memory");

#pragma unroll 1
  for (int c = 0; c < NC2; ++c) {
    const int sel = c % 3;
    if (c + 2 < NC2) STAGE(c + 2);            // 1: deep prefetch (async)

    // 2: compute chunk c (buffer validated by last iteration's wait)
    char* wb = lds + sel * 12288;
    char* xb = lds + 36864 + sel * 4096 + tg * 2048;
    float4 X0 = *(const float4*)(xb + lane * 16);
    float4 X1 = *(const float4*)(xb + 1024 + lane * 16);
    bf16x8 ah, am, al;
    split8(X0, X1, ah, am, al);
    const char* wk = wb + half * 6144 + lane * 16;
#pragma unroll
    for (int f2 = 0; f2 < 2; ++f2) {
      const char* bb = wk + f2 * 3072;
      bf16x8 bh = *(const bf16x8*)(bb);
      bf16x8 bm = *(const bf16x8*)(bb + 1024);
      bf16x8 bl = *(const bf16x8*)(bb + 2048);
      acc[f2] = __builtin_amdgcn_mfma_f32_16x16x32_bf16(ah, bh, acc[f2], 0, 0, 0);
      acc[f2] = __builtin_amdgcn_mfma_f32_16x16x32_bf16(ah, bm, acc[f2], 0, 0, 0);
      acc[f2] = __builtin_amdgcn_mfma_f32_16x16x32_bf16(am, bh, acc[f2], 0, 0, 0);
      acc[f2] = __builtin_amdgcn_mfma_f32_16x16x32_bf16(ah, bl, acc[f2], 0, 0, 0);
      acc[f2] = __builtin_amdgcn_mfma_f32_16x16x32_bf16(al, bh, acc[f2], 0, 0, 0);
      acc[f2] = __builtin_amdgcn_mfma_f32_16x16x32_bf16(am, bm, acc[f2], 0, 0, 0);
    }

    // 3: counted drain -- stage(c+1) done (oldest 4), stage(c+2) in flight
    if (c + 2 < NC2) { asm volatile("s_waitcnt vmcnt(4)" ::: "memory"); }
    else             { asm volatile("s_waitcnt vmcnt(0)" ::: "memory"); }
    __builtin_amdgcn_s_barrier();
    asm volatile("" ::: "memory");
  }
#undef STAGE

  // C frags -> sc[expert][token]. C layout: col(=expert)=lane&15,
  // row(=token)=(lane>>4)*4+reg  [m89-verified]
  float (*sc)[BT + 1] = (float(*)[BT + 1])lds;
#pragma unroll
  for (int f2 = 0; f2 < 2; ++f2) {
    int e = half * 32 + f2 * 16 + (lane & 15);
    int tk = tg * 16 + ((lane >> 4) << 2);
    sc[e][tk + 0] = acc[f2][0];
    sc[e][tk + 1] = acc[f2][1];
    sc[e][tk + 2] = acc[f2][2];
    sc[e][tk + 3] = acc[f2][3];
  }
  __syncthreads();

  // softmax + top-8: 8 lanes per token (t = 0..31), 8 experts per lane
  const int t = tid >> 3;
  const int j = tid & 7;
  float p[8];
#pragma unroll
  for (int i = 0; i < 8; ++i) p[i] = sc[j * 8 + i][t];

  float m = p[0];
#pragma unroll
  for (int i = 1; i < 8; ++i) m = fmaxf(m, p[i]);
  m = fmaxf(m, __shfl_xor(m, 1, 8));
  m = fmaxf(m, __shfl_xor(m, 2, 8));
  m = fmaxf(m, __shfl_xor(m, 4, 8));
  float s = 0.f;
#pragma unroll
  for (int i = 0; i < 8; ++i) { p[i] = __expf(p[i] - m); s += p[i]; }
  s += __shfl_xor(s, 1, 8);
  s += __shfl_xor(s, 2, 8);
  s += __shfl_xor(s, 4, 8);
  float inv = 1.f / s;
#pragma unroll
  for (int i = 0; i < 8; ++i) { p[i] *= inv; sc[j * 8 + i][t] = p[i]; }

  // top-8: strict-> scan (lowest idx on tie), 8-lane (val,idx) reduce
  unsigned used = 0;
  float wsum = 0.f;
  float wv[KTOP];
  int wi_[KTOP];
#pragma unroll
  for (int sel = 0; sel < KTOP; ++sel) {
    float bv = -1.f;
    int bi = 0;
#pragma unroll
    for (int i = 0; i < 8; ++i) {
      bool ok = !((used >> i) & 1u);
      if (ok && p[i] > bv) { bv = p[i]; bi = i; }
    }
    int ge = j * 8 + bi;
#pragma unroll
    for (int mk = 1; mk < 8; mk <<= 1) {
      float ov = __shfl_xor(bv, mk, 8);
      int og = __shfl_xor(ge, mk, 8);
      if (ov > bv || (ov == bv && og < ge)) { bv = ov; ge = og; }
    }
    if ((ge >> 3) == j) used |= 1u << (ge & 7);
    wv[sel] = bv;
    wi_[sel] = ge;
    wsum += bv;
  }
  if (j == 0) {
    float winv = 1.f / (wsum + 1e-20f);
#pragma unroll
    for (int sel = 0; sel < KTOP; ++sel) {
      out[(size_t)(t0 + t) * KTOP + sel] = (float)wi_[sel];
      out[(size_t)TOK * KTOP + (size_t)(t0 + t) * KTOP + sel] = wv[sel] * winv;
      atomicAdd(&hist[wi_[sel]], 1.f);
    }
  }
  __syncthreads();

  if (tid < NE) {
    float ssl = 0.f;
#pragma unroll
    for (int tt = 0; tt < BT; ++tt) ssl += sc[tid][tt];
    atomicAdd(&ssum[b * NE + tid], ssl);
    atomicAdd(&ce[b * NE + tid], hist[tid]);
  }
}

// ---------------------------------------------------------------------------
// Finalize expert_loads + aux_loss (separate kernel: cross-XCD coherence free
// at the launch boundary; no per-block threadfence anywhere).
// ---------------------------------------------------------------------------
__global__ __launch_bounds__(64) void gate_final(const float* __restrict__ ce,
                                                 const float* __restrict__ ssum,
                                                 float* __restrict__ out) {
  const int e = threadIdx.x;
  float loads = 0.f, aux = 0.f;
#pragma unroll
  for (int b = 0; b < NB; ++b) {
    float c = ce[b * 64 + e];
    loads += c;
    aux += (c / 512.0f) * (ssum[b * 64 + e] / 4096.0f);  // (S*K/E)=512, S=4096
  }
  out[(size_t)2 * TOK * KTOP + 1 + e] = loads;
#pragma unroll
  for (int off = 32; off > 0; off >>= 1) aux += __shfl_down(aux, off);
  if (e == 0) out[(size_t)2 * TOK * KTOP] = aux * (0.1f / 4.0f);  // ALPHA/B
}

extern "C" void kernel_launch(void* const* d_in, const int* in_sizes, int n_in,
                              void* d_out, int out_size, void* d_ws, size_t ws_size,
                              hipStream_t stream) {
  const float* x = (const float*)d_in[0];
  const float* w = (const float*)d_in[1];
  float* out = (float*)d_out;

  char* wpk = (char*)d_ws;                         // 32 chunks x 24 KB = 768 KB
  float* ce = (float*)(wpk + (size_t)NC * 24576);  // [NB][NE]
  float* ssum = ce + NB * NE;                      // [NB][NE]

  wsplit<<<dim3(64), dim3(256), 0, stream>>>(w, wpk, ce);
  gate_fused<<<dim3(TOK / BT), dim3(256), 0, stream>>>(x, wpk, out, ce, ssum);
  gate_final<<<dim3(1), dim3(64), 0, stream>>>(ce, ssum, out);
}

// Round 19
// 64.703 us; speedup vs baseline: 1.1218x; 1.1218x over previous
//
#include <hip/hip_runtime.h>
#include <hip/hip_bf16.h>
#include <math.h>

#define TOK 16384
#define HDIM 2048
#define NE 64
#define NB 4
#define KTOP 8
#define KC 64
#define NC (HDIM / KC)   // 32 chunks
#define BT 64            // tokens per block

typedef __attribute__((ext_vector_type(8))) __bf16 bf16x8;
typedef __attribute__((ext_vector_type(4))) float f32x4;
typedef unsigned int uint;

__device__ __forceinline__ uint asu(float f) { union { float f; uint u; } c; c.f = f; return c.u; }
__device__ __forceinline__ float asf(uint u) { union { uint u; float f; } c; c.u = u; return c.f; }

// Exact 3-way bf16 split: h+m+l == x bitwise (8 mantissa bits per plane).
__device__ __forceinline__ void split3(float v, uint& h, uint& m, uint& l) {
  uint u = asu(v);
  h = u & 0xffff0000u;
  float d = v - asf(h);
  m = asu(d) & 0xffff0000u;
  float d2 = d - asf(m);
  l = asu(d2);
}

// 8 floats (one fragment k-slot) -> 3 bf16x8 planes, in-register.
__device__ __forceinline__ void split8(float4 a, float4 b,
                                       bf16x8& h8, bf16x8& m8, bf16x8& l8) {
  union { uint4 u; bf16x8 v; } H, M, L;
  uint h0, m0, l0, h1, m1, l1;
  split3(a.x, h0, m0, l0); split3(a.y, h1, m1, l1);
  H.u.x = (h0 >> 16) | (h1 & 0xffff0000u);
  M.u.x = (m0 >> 16) | (m1 & 0xffff0000u);
  L.u.x = (l0 >> 16) | (l1 & 0xffff0000u);
  split3(a.z, h0, m0, l0); split3(a.w, h1, m1, l1);
  H.u.y = (h0 >> 16) | (h1 & 0xffff0000u);
  M.u.y = (m0 >> 16) | (m1 & 0xffff0000u);
  L.u.y = (l0 >> 16) | (l1 & 0xffff0000u);
  split3(b.x, h0, m0, l0); split3(b.y, h1, m1, l1);
  H.u.z = (h0 >> 16) | (h1 & 0xffff0000u);
  M.u.z = (m0 >> 16) | (m1 & 0xffff0000u);
  L.u.z = (l0 >> 16) | (l1 & 0xffff0000u);
  split3(b.z, h0, m0, l0); split3(b.w, h1, m1, l1);
  H.u.w = (h0 >> 16) | (h1 & 0xffff0000u);
  M.u.w = (m0 >> 16) | (m1 & 0xffff0000u);
  L.u.w = (l0 >> 16) | (l1 & 0xffff0000u);
  h8 = H.v; m8 = M.v; l8 = L.v;
}

__device__ __forceinline__ void gl_lds16(const void* g, void* l) {
  __builtin_amdgcn_global_load_lds(
      (const __attribute__((address_space(1))) void*)g,
      (__attribute__((address_space(3))) void*)l, 16, 0, 0);
}

// ---------------------------------------------------------------------------
// wsplit (r16-verbatim): pack W into B-fragment order, 3 exact bf16 planes;
// zero ce/ssum. byte = c*24576 + ks*12288 + half*6144 + f2*3072
//                     + plane*1024 + lane*16
// ---------------------------------------------------------------------------
__global__ __launch_bounds__(256) void wsplit(const float* __restrict__ w,
                                              char* __restrict__ wpk,
                                              float* __restrict__ stats) {
  if (blockIdx.x == 0 && threadIdx.x < 128) {   // zero ce+ssum (512 floats)
    *(float4*)(stats + threadIdx.x * 4) = make_float4(0.f, 0.f, 0.f, 0.f);
  }
  int t = blockIdx.x * 256 + threadIdx.x;    // 16384 threads
  int lane = t & 63;
  int f2 = (t >> 6) & 1, half = (t >> 7) & 1, ks = (t >> 8) & 1, c = t >> 9;
  int e = half * 32 + f2 * 16 + (lane & 15);
  int k = c * 64 + ks * 32 + ((lane >> 4) << 3);
  const float* p = w + (size_t)e * HDIM + k;
  bf16x8 h8, m8, l8;
  split8(*(const float4*)p, *(const float4*)(p + 4), h8, m8, l8);
  union { bf16x8 v; uint4 u; } H, M, L;
  H.v = h8; M.v = m8; L.v = l8;
  size_t base = (size_t)c * 24576 + (size_t)ks * 12288 + (size_t)half * 6144
              + (size_t)f2 * 3072 + (size_t)lane * 16;
  *(uint4*)(wpk + base) = H.u;
  *(uint4*)(wpk + base + 1024) = M.u;
  *(uint4*)(wpk + base + 2048) = L.u;
}

// ---------------------------------------------------------------------------
// Fused gate. 256 blocks x 512 thr (8 waves), LDS EXACTLY 81920 B so
// 2 blocks/CU = exactly 160 KB. This is r13's BT=64 kernel with its LDS bug
// fixed: r13 declared 81920 + separate hist (82432 total) -> silently fell
// to 1 block/CU, losing the co-resident block that covers each chunk's
// drain (the r9-vs-r13 40% gap). Here hist/sc OVERLAY the staging LDS
// (initialized only after the K-loop).
// W is staged once per 64 tokens (vs r16's 32): device-wide staged bytes
// 524 MB -> 327 MB at the measured delivery-bound rate.
// K-loop: r16 discipline verbatim (all-gl_lds, vmcnt(0)+barrier per chunk,
// no register global loads, no threadfence).
// LDS: W dbuf 2x24K @0, X dbuf 2x16K @49152 = 81920.
// ---------------------------------------------------------------------------
__global__ __launch_bounds__(512, 4) void gate_fused(const float* __restrict__ x,
                                                     const char* __restrict__ wpk,
                                                     float* __restrict__ out,
                                                     float* __restrict__ ce,
                                                     float* __restrict__ ssum) {
  __shared__ __align__(16) char lds[81920];   // [W0|W1|X0|X1] -- NOTHING else

  const int tid = threadIdx.x;
  const int bid = blockIdx.x;
  const int t0 = bid * BT;
  const int b = bid >> 6;                     // 64 blocks per batch row
  const int lane = tid & 63;
  const int wid = tid >> 6;                   // 0..7
  const int half = wid & 1;                   // expert half
  const int tg = wid >> 1;                    // token group 0..3 (16 tok each)

  // X staging (r13-verified): 2 slots/thread, s = r*512 + tid =
  // [stg(2b)][sks(1b)][sq(1b)][ln(6b)]; content
  // x[t0 + stg*16 + (ln&15)][c*64 + sks*32 + (ln>>4)*8 + sq*4 .. +3]
  const char* xsg[2];
  int xdo_[2];
#pragma unroll
  for (int r = 0; r < 2; ++r) {
    int s = r * 512 + tid;
    int stg = s >> 8, sks = (s >> 7) & 1, sq = (s >> 6) & 1, ln = s & 63;
    xsg[r] = (const char*)(x + (size_t)(t0 + stg * 16 + (ln & 15)) * HDIM
                           + sks * 32 + ((ln >> 4) << 3) + sq * 4);
    xdo_[r] = (r * 512 + wid * 64) * 16;      // wave-uniform dest offset
  }
  const char* wsrc = wpk + (size_t)lane * 16;

  f32x4 acc[2] = {{0.f, 0.f, 0.f, 0.f}, {0.f, 0.f, 0.f, 0.f}};

#define STAGE(cc, sel)                                                        \
  {                                                                           \
    const char* wp_ = wsrc + (size_t)(cc) * 24576;                            \
    char* wd_ = lds + (sel) * 24576;                                          \
    _Pragma("unroll")                                                         \
    for (int i = 0; i < 3; ++i)                                               \
      gl_lds16(wp_ + (i * 8 + wid) * 1024, wd_ + (i * 8 + wid) * 1024);       \
    char* xdst = lds + 49152 + (sel) * 16384;                                 \
    _Pragma("unroll")                                                         \
    for (int r = 0; r < 2; ++r)                                               \
      gl_lds16(xsg[r] + (size_t)(cc) * 256, xdst + xdo_[r]);                  \
  }

  // ---- prologue: stage chunk 0, drain, barrier
  STAGE(0, 0);
  asm volatile("s_waitcnt vmcnt(0)" ::: "memory");
  __builtin_amdgcn_s_barrier();
  asm volatile("" ::: "memory");

#pragma unroll 1
  for (int c = 0; c < NC; ++c) {
    const int sel = c & 1;
    if (c + 1 < NC) STAGE(c + 1, sel ^ 1);    // 1: stage next chunk (async)

    char* wb = lds + sel * 24576;
    char* xb = lds + 49152 + sel * 16384 + tg * 4096;
#pragma unroll
    for (int ks = 0; ks < 2; ++ks) {          // 2: X from LDS, split, MFMA
      float4 X0 = *(const float4*)(xb + ks * 2048 + lane * 16);
      float4 X1 = *(const float4*)(xb + ks * 2048 + 1024 + lane * 16);
      bf16x8 ah, am, al;
      split8(X0, X1, ah, am, al);
      const char* wk = wb + ks * 12288 + half * 6144 + lane * 16;
#pragma unroll
      for (int f2 = 0; f2 < 2; ++f2) {
        const char* bb = wk + f2 * 3072;
        bf16x8 bh = *(const bf16x8*)(bb);
        bf16x8 bm = *(const bf16x8*)(bb + 1024);
        bf16x8 bl = *(const bf16x8*)(bb + 2048);
        acc[f2] = __builtin_amdgcn_mfma_f32_16x16x32_bf16(ah, bh, acc[f2], 0, 0, 0);
        acc[f2] = __builtin_amdgcn_mfma_f32_16x16x32_bf16(ah, bm, acc[f2], 0, 0, 0);
        acc[f2] = __builtin_amdgcn_mfma_f32_16x16x32_bf16(am, bh, acc[f2], 0, 0, 0);
        acc[f2] = __builtin_amdgcn_mfma_f32_16x16x32_bf16(ah, bl, acc[f2], 0, 0, 0);
        acc[f2] = __builtin_amdgcn_mfma_f32_16x16x32_bf16(al, bh, acc[f2], 0, 0, 0);
        acc[f2] = __builtin_amdgcn_mfma_f32_16x16x32_bf16(am, bm, acc[f2], 0, 0, 0);
      }
    }
    // 3: drain the staging issued at top of THIS chunk; barrier
    asm volatile("s_waitcnt vmcnt(0)" ::: "memory");
    __builtin_amdgcn_s_barrier();
    asm volatile("" ::: "memory");
  }
#undef STAGE

  // ---- epilogue overlays (only AFTER the K-loop's final barrier):
  // sc[64][65] @ lds+0 (16640 B, inside old W0); hist @ lds+49152.
  float (*sc)[BT + 1] = (float(*)[BT + 1])lds;
  float* hist = (float*)(lds + 49152);
  if (tid < NE) hist[tid] = 0.f;

  // C frags -> sc[expert][token]. C layout: col(=expert)=lane&15,
  // row(=token)=(lane>>4)*4+reg  [m89-verified]
#pragma unroll
  for (int f2 = 0; f2 < 2; ++f2) {
    int e = half * 32 + f2 * 16 + (lane & 15);
    int tk = tg * 16 + ((lane >> 4) << 2);
    sc[e][tk + 0] = acc[f2][0];
    sc[e][tk + 1] = acc[f2][1];
    sc[e][tk + 2] = acc[f2][2];
    sc[e][tk + 3] = acc[f2][3];
  }
  __syncthreads();

  // softmax + top-8: 8 lanes per token (t = 0..63), 8 experts per lane
  const int t = tid >> 3;
  const int j = tid & 7;
  float p[8];
#pragma unroll
  for (int i = 0; i < 8; ++i) p[i] = sc[j * 8 + i][t];

  float m = p[0];
#pragma unroll
  for (int i = 1; i < 8; ++i) m = fmaxf(m, p[i]);
  m = fmaxf(m, __shfl_xor(m, 1, 8));
  m = fmaxf(m, __shfl_xor(m, 2, 8));
  m = fmaxf(m, __shfl_xor(m, 4, 8));
  float s = 0.f;
#pragma unroll
  for (int i = 0; i < 8; ++i) { p[i] = __expf(p[i] - m); s += p[i]; }
  s += __shfl_xor(s, 1, 8);
  s += __shfl_xor(s, 2, 8);
  s += __shfl_xor(s, 4, 8);
  float inv = 1.f / s;
#pragma unroll
  for (int i = 0; i < 8; ++i) { p[i] *= inv; sc[j * 8 + i][t] = p[i]; }

  // top-8: strict-> scan (lowest idx on tie), 8-lane (val,idx) reduce
  unsigned used = 0;
  float wsum = 0.f;
  float wv[KTOP];
  int wi_[KTOP];
#pragma unroll
  for (int sel = 0; sel < KTOP; ++sel) {
    float bv = -1.f;
    int bi = 0;
#pragma unroll
    for (int i = 0; i < 8; ++i) {
      bool ok = !((used >> i) & 1u);
      if (ok && p[i] > bv) { bv = p[i]; bi = i; }
    }
    int ge = j * 8 + bi;
#pragma unroll
    for (int mk = 1; mk < 8; mk <<= 1) {
      float ov = __shfl_xor(bv, mk, 8);
      int og = __shfl_xor(ge, mk, 8);
      if (ov > bv || (ov == bv && og < ge)) { bv = ov; ge = og; }
    }
    if ((ge >> 3) == j) used |= 1u << (ge & 7);
    wv[sel] = bv;
    wi_[sel] = ge;
    wsum += bv;
  }
  if (j == 0) {
    float winv = 1.f / (wsum + 1e-20f);
#pragma unroll
    for (int sel = 0; sel < KTOP; ++sel) {
      out[(size_t)(t0 + t) * KTOP + sel] = (float)wi_[sel];
      out[(size_t)TOK * KTOP + (size_t)(t0 + t) * KTOP + sel] = wv[sel] * winv;
      atomicAdd(&hist[wi_[sel]], 1.f);
    }
  }
  __syncthreads();

  if (tid < NE) {
    float ssl = 0.f;
#pragma unroll
    for (int tt = 0; tt < BT; ++tt) ssl += sc[tid][tt];
    atomicAdd(&ssum[b * NE + tid], ssl);
    atomicAdd(&ce[b * NE + tid], hist[tid]);
  }
}

// ---------------------------------------------------------------------------
// Finalize expert_loads + aux_loss (separate kernel: cross-XCD coherence free
// at the launch boundary; no per-block threadfence anywhere).
// ---------------------------------------------------------------------------
__global__ __launch_bounds__(64) void gate_final(const float* __restrict__ ce,
                                                 const float* __restrict__ ssum,
                                                 float* __restrict__ out) {
  const int e = threadIdx.x;
  float loads = 0.f, aux = 0.f;
#pragma unroll
  for (int b = 0; b < NB; ++b) {
    float c = ce[b * 64 + e];
    loads += c;
    aux += (c / 512.0f) * (ssum[b * 64 + e] / 4096.0f);  // (S*K/E)=512, S=4096
  }
  out[(size_t)2 * TOK * KTOP + 1 + e] = loads;
#pragma unroll
  for (int off = 32; off > 0; off >>= 1) aux += __shfl_down(aux, off);
  if (e == 0) out[(size_t)2 * TOK * KTOP] = aux * (0.1f / 4.0f);  // ALPHA/B
}

extern "C" void kernel_launch(void* const* d_in, const int* in_sizes, int n_in,
                              void* d_out, int out_size, void* d_ws, size_t ws_size,
                              hipStream_t stream) {
  const float* x = (const float*)d_in[0];
  const float* w = (const float*)d_in[1];
  float* out = (float*)d_out;

  char* wpk = (char*)d_ws;                         // 32 chunks x 24 KB = 768 KB
  float* ce = (float*)(wpk + (size_t)NC * 24576);  // [NB][NE]
  float* ssum = ce + NB * NE;                      // [NB][NE]

  wsplit<<<dim3(64), dim3(256), 0, stream>>>(w, wpk, ce);
  gate_fused<<<dim3(TOK / BT), dim3(512), 0, stream>>>(x, wpk, out, ce, ssum);
  gate_final<<<dim3(1), dim3(64), 0, stream>>>(ce, ssum, out);
}

// Round 20
// 58.996 us; speedup vs baseline: 1.2304x; 1.0967x over previous
//
#include <hip/hip_runtime.h>
#include <hip/hip_bf16.h>
#include <math.h>

#define TOK 16384
#define HDIM 2048
#define NE 64
#define NB 4
#define KTOP 8
#define KC 64
#define NC (HDIM / KC)   // 32 chunks
#define BT 32            // tokens per block

typedef __attribute__((ext_vector_type(8))) __bf16 bf16x8;
typedef __attribute__((ext_vector_type(4))) float f32x4;
typedef unsigned int uint;

__device__ __forceinline__ uint asu(float f) { union { float f; uint u; } c; c.f = f; return c.u; }
__device__ __forceinline__ float asf(uint u) { union { uint u; float f; } c; c.u = u; return c.f; }

// Exact 3-way bf16 split: h+m+l == x bitwise (8 mantissa bits per plane).
__device__ __forceinline__ void split3(float v, uint& h, uint& m, uint& l) {
  uint u = asu(v);
  h = u & 0xffff0000u;
  float d = v - asf(h);
  m = asu(d) & 0xffff0000u;
  float d2 = d - asf(m);
  l = asu(d2);
}

// 8 floats (one fragment k-slot) -> 3 bf16x8 planes, in-register.
__device__ __forceinline__ void split8(float4 a, float4 b,
                                       bf16x8& h8, bf16x8& m8, bf16x8& l8) {
  union { uint4 u; bf16x8 v; } H, M, L;
  uint h0, m0, l0, h1, m1, l1;
  split3(a.x, h0, m0, l0); split3(a.y, h1, m1, l1);
  H.u.x = (h0 >> 16) | (h1 & 0xffff0000u);
  M.u.x = (m0 >> 16) | (m1 & 0xffff0000u);
  L.u.x = (l0 >> 16) | (l1 & 0xffff0000u);
  split3(a.z, h0, m0, l0); split3(a.w, h1, m1, l1);
  H.u.y = (h0 >> 16) | (h1 & 0xffff0000u);
  M.u.y = (m0 >> 16) | (m1 & 0xffff0000u);
  L.u.y = (l0 >> 16) | (l1 & 0xffff0000u);
  split3(b.x, h0, m0, l0); split3(b.y, h1, m1, l1);
  H.u.z = (h0 >> 16) | (h1 & 0xffff0000u);
  M.u.z = (m0 >> 16) | (m1 & 0xffff0000u);
  L.u.z = (l0 >> 16) | (l1 & 0xffff0000u);
  split3(b.z, h0, m0, l0); split3(b.w, h1, m1, l1);
  H.u.w = (h0 >> 16) | (h1 & 0xffff0000u);
  M.u.w = (m0 >> 16) | (m1 & 0xffff0000u);
  L.u.w = (l0 >> 16) | (l1 & 0xffff0000u);
  h8 = H.v; m8 = M.v; l8 = L.v;
}

__device__ __forceinline__ void gl_lds16(const void* g, void* l) {
  __builtin_amdgcn_global_load_lds(
      (const __attribute__((address_space(1))) void*)g,
      (__attribute__((address_space(3))) void*)l, 16, 0, 0);
}

// ---------------------------------------------------------------------------
// wsplit: pack W into B-fragment order, 3 exact bf16 planes; zero ce/ssum.
// byte addr = c*24576 + ks*12288 + half*6144 + f2*3072 + plane*1024 + lane*16
// Fragment (c,ks,half,f2,plane,lane): e = half*32+f2*16+(lane&15),
//                                     k = c*64+ks*32+(lane>>4)*8
// ---------------------------------------------------------------------------
__global__ __launch_bounds__(256) void wsplit(const float* __restrict__ w,
                                              char* __restrict__ wpk,
                                              float* __restrict__ stats) {
  if (blockIdx.x == 0 && threadIdx.x < 128) {   // zero ce+ssum (512 floats)
    *(float4*)(stats + threadIdx.x * 4) = make_float4(0.f, 0.f, 0.f, 0.f);
  }
  int t = blockIdx.x * 256 + threadIdx.x;    // 16384 threads
  int lane = t & 63;
  int f2 = (t >> 6) & 1, half = (t >> 7) & 1, ks = (t >> 8) & 1, c = t >> 9;
  int e = half * 32 + f2 * 16 + (lane & 15);
  int k = c * 64 + ks * 32 + ((lane >> 4) << 3);
  const float* p = w + (size_t)e * HDIM + k;
  bf16x8 h8, m8, l8;
  split8(*(const float4*)p, *(const float4*)(p + 4), h8, m8, l8);
  union { bf16x8 v; uint4 u; } H, M, L;
  H.v = h8; M.v = m8; L.v = l8;
  size_t base = (size_t)c * 24576 + (size_t)ks * 12288 + (size_t)half * 6144
              + (size_t)f2 * 3072 + (size_t)lane * 16;
  *(uint4*)(wpk + base) = H.u;
  *(uint4*)(wpk + base + 1024) = M.u;
  *(uint4*)(wpk + base + 2048) = L.u;
}

// ---------------------------------------------------------------------------
// Fused gate (r16-exact, session best 58.65 us; ~87% of the measured
// ~20 B/cy/CU global->LDS staging-delivery ceiling for its 64 KB/chunk/CU
// ledger). 512 blocks x 256 thr (4 waves), 2 blocks/CU.
// Wave = 16 tokens x 32 experts (2 C-frags).
// K-loop has NO register global loads: X and W both staged via
// global_load_lds (X: per-lane fragment-swizzled source, m173 pattern).
// One s_waitcnt vmcnt(0) + s_barrier per chunk; the co-resident block
// covers the drain. NO __threadfence anywhere (r15: ~35 us poison).
// LDS: W dbuf 2x24KB @0, X dbuf 2x8KB @49152. 64KB total -> 2 blocks/CU.
// ---------------------------------------------------------------------------
__global__ __launch_bounds__(256, 2) void gate_fused(const float* __restrict__ x,
                                                     const char* __restrict__ wpk,
                                                     float* __restrict__ out,
                                                     float* __restrict__ ce,
                                                     float* __restrict__ ssum) {
  __shared__ __align__(16) char lds[65536];   // [W0|W1|X0|X1]
  __shared__ float hist[NE];

  const int tid = threadIdx.x;
  const int bid = blockIdx.x;
  const int t0 = bid * BT;
  const int b = bid >> 7;                     // 128 blocks per batch row
  const int lane = tid & 63;
  const int wid = tid >> 6;                   // 0..3
  const int half = wid & 1;                   // expert half
  const int tg = (wid >> 1);                  // token group: 0 or 1

  if (tid < NE) hist[tid] = 0.f;

  // X staging: 2 slots per thread, s = r*256 + tid. Source is per-lane
  // (fragment-swizzled); dest base is wave-uniform (s>>6 constant per wave).
  const char* xsg[2];
  int xdo_[2];
#pragma unroll
  for (int r = 0; r < 2; ++r) {
    int s = r * 256 + tid;
    int stg = s >> 8, sks = (s >> 7) & 1, sq = (s >> 6) & 1, ln = s & 63;
    xsg[r] = (const char*)(x + (size_t)(t0 + stg * 16 + (ln & 15)) * HDIM
                           + sks * 32 + ((ln >> 4) << 3) + sq * 4);
    xdo_[r] = (r * 256 + wid * 64) * 16;      // wave-uniform dest offset
  }
  const char* wsrc = wpk + (size_t)lane * 16;

  f32x4 acc[2] = {{0.f, 0.f, 0.f, 0.f}, {0.f, 0.f, 0.f, 0.f}};

#define STAGE(cc, sel)                                                        \
  {                                                                           \
    char* wdst = lds + (sel) * 24576;                                         \
    const char* wp_ = wsrc + (size_t)(cc) * 24576;                            \
    _Pragma("unroll")                                                         \
    for (int i = 0; i < 6; ++i)                                               \
      gl_lds16(wp_ + (i * 4 + wid) * 1024, wdst + (i * 4 + wid) * 1024);      \
    char* xdst = lds + 49152 + (sel) * 8192;                                  \
    _Pragma("unroll")                                                         \
    for (int r = 0; r < 2; ++r)                                               \
      gl_lds16(xsg[r] + (size_t)(cc) * 256, xdst + xdo_[r]);                  \
  }

  // ---- prologue: stage chunk 0, drain, barrier
  STAGE(0, 0);
  asm volatile("s_waitcnt vmcnt(0)" ::: "memory");
  __builtin_amdgcn_s_barrier();
  asm volatile("" ::: "memory");

#pragma unroll 1
  for (int c = 0; c < NC; ++c) {
    const int sel = c & 1;
    if (c + 1 < NC) STAGE(c + 1, sel ^ 1);    // 1: stage next chunk (async)

    char* wb = lds + sel * 24576;
    char* xb = lds + 49152 + sel * 8192 + tg * 4096;
#pragma unroll
    for (int ks = 0; ks < 2; ++ks) {          // 2: X from LDS, split, MFMA
      float4 X0 = *(const float4*)(xb + ks * 2048 + lane * 16);
      float4 X1 = *(const float4*)(xb + ks * 2048 + 1024 + lane * 16);
      bf16x8 ah, am, al;
      split8(X0, X1, ah, am, al);
      const char* wk = wb + ks * 12288 + half * 6144 + lane * 16;
#pragma unroll
      for (int f2 = 0; f2 < 2; ++f2) {
        const char* bb = wk + f2 * 3072;
        bf16x8 bh = *(const bf16x8*)(bb);
        bf16x8 bm = *(const bf16x8*)(bb + 1024);
        bf16x8 bl = *(const bf16x8*)(bb + 2048);
        acc[f2] = __builtin_amdgcn_mfma_f32_16x16x32_bf16(ah, bh, acc[f2], 0, 0, 0);
        acc[f2] = __builtin_amdgcn_mfma_f32_16x16x32_bf16(ah, bm, acc[f2], 0, 0, 0);
        acc[f2] = __builtin_amdgcn_mfma_f32_16x16x32_bf16(am, bh, acc[f2], 0, 0, 0);
        acc[f2] = __builtin_amdgcn_mfma_f32_16x16x32_bf16(ah, bl, acc[f2], 0, 0, 0);
        acc[f2] = __builtin_amdgcn_mfma_f32_16x16x32_bf16(al, bh, acc[f2], 0, 0, 0);
        acc[f2] = __builtin_amdgcn_mfma_f32_16x16x32_bf16(am, bm, acc[f2], 0, 0, 0);
      }
    }
    // 3: drain the staging issued at top of THIS chunk (full chunk in flight)
    asm volatile("s_waitcnt vmcnt(0)" ::: "memory");
    __builtin_amdgcn_s_barrier();
    asm volatile("" ::: "memory");
  }
#undef STAGE

  // C frags -> sc[expert][token]. C layout: col(=expert)=lane&15,
  // row(=token)=(lane>>4)*4+reg  [m89-verified]
  float (*sc)[BT + 1] = (float(*)[BT + 1])lds;
#pragma unroll
  for (int f2 = 0; f2 < 2; ++f2) {
    int e = half * 32 + f2 * 16 + (lane & 15);
    int tk = tg * 16 + ((lane >> 4) << 2);
    sc[e][tk + 0] = acc[f2][0];
    sc[e][tk + 1] = acc[f2][1];
    sc[e][tk + 2] = acc[f2][2];
    sc[e][tk + 3] = acc[f2][3];
  }
  __syncthreads();

  // softmax + top-8: 8 lanes per token (t = 0..31), 8 experts per lane
  const int t = tid >> 3;
  const int j = tid & 7;
  float p[8];
#pragma unroll
  for (int i = 0; i < 8; ++i) p[i] = sc[j * 8 + i][t];

  float m = p[0];
#pragma unroll
  for (int i = 1; i < 8; ++i) m = fmaxf(m, p[i]);
  m = fmaxf(m, __shfl_xor(m, 1, 8));
  m = fmaxf(m, __shfl_xor(m, 2, 8));
  m = fmaxf(m, __shfl_xor(m, 4, 8));
  float s = 0.f;
#pragma unroll
  for (int i = 0; i < 8; ++i) { p[i] = __expf(p[i] - m); s += p[i]; }
  s += __shfl_xor(s, 1, 8);
  s += __shfl_xor(s, 2, 8);
  s += __shfl_xor(s, 4, 8);
  float inv = 1.f / s;
#pragma unroll
  for (int i = 0; i < 8; ++i) { p[i] *= inv; sc[j * 8 + i][t] = p[i]; }

  // top-8: strict-> scan (lowest idx on tie), 8-lane (val,idx) reduce
  unsigned used = 0;
  float wsum = 0.f;
  float wv[KTOP];
  int wi_[KTOP];
#pragma unroll
  for (int sel = 0; sel < KTOP; ++sel) {
    float bv = -1.f;
    int bi = 0;
#pragma unroll
    for (int i = 0; i < 8; ++i) {
      bool ok = !((used >> i) & 1u);
      if (ok && p[i] > bv) { bv = p[i]; bi = i; }
    }
    int ge = j * 8 + bi;
#pragma unroll
    for (int mk = 1; mk < 8; mk <<= 1) {
      float ov = __shfl_xor(bv, mk, 8);
      int og = __shfl_xor(ge, mk, 8);
      if (ov > bv || (ov == bv && og < ge)) { bv = ov; ge = og; }
    }
    if ((ge >> 3) == j) used |= 1u << (ge & 7);
    wv[sel] = bv;
    wi_[sel] = ge;
    wsum += bv;
  }
  if (j == 0) {
    float winv = 1.f / (wsum + 1e-20f);
#pragma unroll
    for (int sel = 0; sel < KTOP; ++sel) {
      out[(size_t)(t0 + t) * KTOP + sel] = (float)wi_[sel];
      out[(size_t)TOK * KTOP + (size_t)(t0 + t) * KTOP + sel] = wv[sel] * winv;
      atomicAdd(&hist[wi_[sel]], 1.f);
    }
  }
  __syncthreads();

  if (tid < NE) {
    float ssl = 0.f;
#pragma unroll
    for (int tt = 0; tt < BT; ++tt) ssl += sc[tid][tt];
    atomicAdd(&ssum[b * NE + tid], ssl);
    atomicAdd(&ce[b * NE + tid], hist[tid]);
  }
}

// ---------------------------------------------------------------------------
// Finalize expert_loads + aux_loss (separate kernel: cross-XCD coherence free
// at the launch boundary; no per-block threadfence anywhere).
// ---------------------------------------------------------------------------
__global__ __launch_bounds__(64) void gate_final(const float* __restrict__ ce,
                                                 const float* __restrict__ ssum,
                                                 float* __restrict__ out) {
  const int e = threadIdx.x;
  float loads = 0.f, aux = 0.f;
#pragma unroll
  for (int b = 0; b < NB; ++b) {
    float c = ce[b * 64 + e];
    loads += c;
    aux += (c / 512.0f) * (ssum[b * 64 + e] / 4096.0f);  // (S*K/E)=512, S=4096
  }
  out[(size_t)2 * TOK * KTOP + 1 + e] = loads;
#pragma unroll
  for (int off = 32; off > 0; off >>= 1) aux += __shfl_down(aux, off);
  if (e == 0) out[(size_t)2 * TOK * KTOP] = aux * (0.1f / 4.0f);  // ALPHA/B
}

extern "C" void kernel_launch(void* const* d_in, const int* in_sizes, int n_in,
                              void* d_out, int out_size, void* d_ws, size_t ws_size,
                              hipStream_t stream) {
  const float* x = (const float*)d_in[0];
  const float* w = (const float*)d_in[1];
  float* out = (float*)d_out;

  char* wpk = (char*)d_ws;                         // 32 chunks x 24 KB = 768 KB
  float* ce = (float*)(wpk + (size_t)NC * 24576);  // [NB][NE]
  float* ssum = ce + NB * NE;                      // [NB][NE]

  wsplit<<<dim3(64), dim3(256), 0, stream>>>(w, wpk, ce);
  gate_fused<<<dim3(TOK / BT), dim3(256), 0, stream>>>(x, wpk, out, ce, ssum);
  gate_final<<<dim3(1), dim3(64), 0, stream>>>(ce, ssum, out);
}